// Round 1
// baseline (522.420 us; speedup 1.0000x reference)
//
#include <hip/hip_runtime.h>
#include <hip/hip_bf16.h>

typedef __attribute__((ext_vector_type(4))) float f32x4;
typedef __attribute__((ext_vector_type(8))) __bf16 bf16x8;

#define EMB 1024
#define NHEAD 16
#define HDIM 64
#define SEQ 2048
#define BATCH 4

__device__ __forceinline__ unsigned short f2bf(float f) {
    unsigned int u = __builtin_bit_cast(unsigned int, f);
    u = (u + 0x7fffu + ((u >> 16) & 1u)) >> 16;
    return (unsigned short)u;
}

// ---------------- fp32 -> bf16 convert ----------------
__global__ void cvt_f32_bf16(const float4* __restrict__ in, ushort* __restrict__ out, int n4) {
    int i = blockIdx.x * 256 + threadIdx.x;
    if (i < n4) {
        float4 v = in[i];
        ushort4 o;
        o.x = f2bf(v.x); o.y = f2bf(v.y); o.z = f2bf(v.z); o.w = f2bf(v.w);
        ((ushort4*)out)[i] = o;
    }
}

// ---------------- QKV GEMM: [8192,1024]bf16 @ [3072,1024]^T + bias ----------------
// Scatter epilogue: Q[B,H,S,D], K[B,H,S,D], Vt[B,H,D,S]  (all bf16)
__global__ __launch_bounds__(256) void gemm_qkv(
    const ushort* __restrict__ A,     // [8192,1024]
    const ushort* __restrict__ W,     // [3072,1024]
    const float*  __restrict__ bias,  // [3072]
    ushort* __restrict__ Qb, ushort* __restrict__ Kb, ushort* __restrict__ Vt)
{
    __shared__ ushort As[64][40];
    __shared__ ushort Bs[64][40];
    const int tid  = threadIdx.x;
    const int lane = tid & 63;
    const int wave = tid >> 6;
    const int col  = lane & 15;
    const int quad = lane >> 4;
    const int m0 = blockIdx.x * 64;
    const int n0 = blockIdx.y * 64;
    const int wm = (wave >> 1) * 32;
    const int wn = (wave & 1) * 32;

    const int lr = tid >> 2;        // 0..63
    const int lc = (tid & 3) * 8;   // 0,8,16,24
    const ushort* Aptr = A + (size_t)(m0 + lr) * EMB + lc;
    const ushort* Bptr = W + (size_t)(n0 + lr) * EMB + lc;

    f32x4 acc[2][2] = {};
    for (int kt = 0; kt < EMB / 32; ++kt) {
        uint4 av = *(const uint4*)(Aptr + kt * 32);
        uint4 bv = *(const uint4*)(Bptr + kt * 32);
        *(uint4*)&As[lr][lc] = av;
        *(uint4*)&Bs[lr][lc] = bv;
        __syncthreads();
        bf16x8 a0 = *(const bf16x8*)&As[wm + col][quad * 8];
        bf16x8 a1 = *(const bf16x8*)&As[wm + 16 + col][quad * 8];
        bf16x8 b0 = *(const bf16x8*)&Bs[wn + col][quad * 8];
        bf16x8 b1 = *(const bf16x8*)&Bs[wn + 16 + col][quad * 8];
        acc[0][0] = __builtin_amdgcn_mfma_f32_16x16x32_bf16(a0, b0, acc[0][0], 0, 0, 0);
        acc[0][1] = __builtin_amdgcn_mfma_f32_16x16x32_bf16(a0, b1, acc[0][1], 0, 0, 0);
        acc[1][0] = __builtin_amdgcn_mfma_f32_16x16x32_bf16(a1, b0, acc[1][0], 0, 0, 0);
        acc[1][1] = __builtin_amdgcn_mfma_f32_16x16x32_bf16(a1, b1, acc[1][1], 0, 0, 0);
        __syncthreads();
    }

    // epilogue: bias + scatter
    for (int i = 0; i < 2; ++i)
        for (int j = 0; j < 2; ++j)
            for (int r = 0; r < 4; ++r) {
                int m = m0 + wm + i * 16 + quad * 4 + r;   // 0..8191  (b*2048+s)
                int n = n0 + wn + j * 16 + col;            // 0..3071
                float v = acc[i][j][r] + bias[n];
                unsigned short bv = f2bf(v);
                int which = n >> 10;
                int e = n & 1023;
                int h = e >> 6, d = e & 63;
                int b = m >> 11, s = m & 2047;
                size_t bh = (size_t)(b * NHEAD + h);
                if (which == 0)      Qb[(bh * SEQ + s) * HDIM + d] = bv;
                else if (which == 1) Kb[(bh * SEQ + s) * HDIM + d] = bv;
                else                 Vt[(bh * HDIM + d) * SEQ + s] = bv;
            }
}

// ---------------- Flash attention (causal), bf16 MFMA ----------------
// grid: (64 head-batches, 32 q-blocks of 64); block 256 (4 waves x 16 q-rows)
__global__ __launch_bounds__(256) void attn(
    const ushort* __restrict__ Qb, const ushort* __restrict__ Kb,
    const ushort* __restrict__ Vt, ushort* __restrict__ Yb)
{
    __shared__ ushort P[4][16][40];
    const int bh   = blockIdx.x;   // b*16+h
    const int qb   = blockIdx.y;   // 0..31
    const int wave = threadIdx.x >> 6;
    const int lane = threadIdx.x & 63;
    const int col  = lane & 15;
    const int quad = lane >> 4;
    const int q0   = qb * 64 + wave * 16;

    const ushort* Qh = Qb + (size_t)bh * SEQ * HDIM;
    const ushort* Kh = Kb + (size_t)bh * SEQ * HDIM;
    const ushort* Vh = Vt + (size_t)bh * HDIM * SEQ;

    bf16x8 qf0 = *(const bf16x8*)(Qh + (q0 + col) * HDIM + quad * 8);
    bf16x8 qf1 = *(const bf16x8*)(Qh + (q0 + col) * HDIM + 32 + quad * 8);

    f32x4 o[4] = {};
    float mrun[4], lrun[4];
    for (int r = 0; r < 4; ++r) { mrun[r] = -INFINITY; lrun[r] = 0.f; }

    const int ktmax = 2 * qb + 2;
    for (int kt = 0; kt < ktmax; ++kt) {
        // ---- scores: Q @ K^T for 32 key columns ----
        const ushort* kb0 = Kh + (kt * 32 + col) * HDIM + quad * 8;
        const ushort* kb1 = kb0 + 16 * HDIM;
        bf16x8 k00 = *(const bf16x8*)(kb0);
        bf16x8 k01 = *(const bf16x8*)(kb0 + 32);
        bf16x8 k10 = *(const bf16x8*)(kb1);
        bf16x8 k11 = *(const bf16x8*)(kb1 + 32);
        f32x4 zero = {0.f, 0.f, 0.f, 0.f};
        f32x4 s0 = __builtin_amdgcn_mfma_f32_16x16x32_bf16(qf0, k00, zero, 0, 0, 0);
        s0 = __builtin_amdgcn_mfma_f32_16x16x32_bf16(qf1, k01, s0, 0, 0, 0);
        f32x4 s1 = __builtin_amdgcn_mfma_f32_16x16x32_bf16(qf0, k10, zero, 0, 0, 0);
        s1 = __builtin_amdgcn_mfma_f32_16x16x32_bf16(qf1, k11, s1, 0, 0, 0);

        // ---- online softmax over 32 columns ----
        const int c0 = kt * 32 + col;
        const int c1 = c0 + 16;
        float p0[4], p1[4], alpha[4];
        for (int r = 0; r < 4; ++r) {
            int row = q0 + quad * 4 + r;
            float v0 = (c0 <= row) ? s0[r] * 0.125f : -INFINITY;
            float v1 = (c1 <= row) ? s1[r] * 0.125f : -INFINITY;
            float mx = fmaxf(v0, v1);
            for (int off = 1; off < 16; off <<= 1)
                mx = fmaxf(mx, __shfl_xor(mx, off, 64));
            float mnew = fmaxf(mrun[r], mx);
            alpha[r] = __expf(mrun[r] - mnew);
            p0[r] = __expf(v0 - mnew);
            p1[r] = __expf(v1 - mnew);
            float rs = p0[r] + p1[r];
            for (int off = 1; off < 16; off <<= 1)
                rs += __shfl_xor(rs, off, 64);
            lrun[r] = lrun[r] * alpha[r] + rs;
            mrun[r] = mnew;
        }
        for (int dt = 0; dt < 4; ++dt)
            for (int r = 0; r < 4; ++r)
                o[dt][r] *= alpha[r];

        // ---- P: C-layout -> LDS -> A-operand layout ----
        for (int r = 0; r < 4; ++r) {
            P[wave][quad * 4 + r][col]      = f2bf(p0[r]);
            P[wave][quad * 4 + r][16 + col] = f2bf(p1[r]);
        }
        __syncthreads();
        bf16x8 pf = *(const bf16x8*)&P[wave][col][quad * 8];
        __syncthreads();

        // ---- O += P @ V ----
        for (int dt = 0; dt < 4; ++dt) {
            bf16x8 vf = *(const bf16x8*)(Vh + (dt * 16 + col) * SEQ + kt * 32 + quad * 8);
            o[dt] = __builtin_amdgcn_mfma_f32_16x16x32_bf16(pf, vf, o[dt], 0, 0, 0);
        }
    }

    // ---- epilogue: O/l -> Y[b, s, h*64+d] bf16 ----
    const int b = bh >> 4, h = bh & 15;
    for (int r = 0; r < 4; ++r) {
        float inv = 1.f / lrun[r];
        int srow = q0 + quad * 4 + r;
        size_t base = ((size_t)(b * SEQ + srow)) * EMB + h * HDIM;
        for (int dt = 0; dt < 4; ++dt)
            Yb[base + dt * 16 + col] = f2bf(o[dt][r] * inv);
    }
}

// ---------------- Output proj: [8192,1024]bf16 @ [1024,1024]^T + bias -> fp32 ----------------
__global__ __launch_bounds__(256) void gemm_proj(
    const ushort* __restrict__ A,     // [8192,1024]
    const ushort* __restrict__ W,     // [1024,1024]
    const float*  __restrict__ bias,  // [1024]
    float* __restrict__ out)          // [8192,1024]
{
    __shared__ ushort As[64][40];
    __shared__ ushort Bs[64][40];
    const int tid  = threadIdx.x;
    const int lane = tid & 63;
    const int wave = tid >> 6;
    const int col  = lane & 15;
    const int quad = lane >> 4;
    const int m0 = blockIdx.x * 64;
    const int n0 = blockIdx.y * 64;
    const int wm = (wave >> 1) * 32;
    const int wn = (wave & 1) * 32;

    const int lr = tid >> 2;
    const int lc = (tid & 3) * 8;
    const ushort* Aptr = A + (size_t)(m0 + lr) * EMB + lc;
    const ushort* Bptr = W + (size_t)(n0 + lr) * EMB + lc;

    f32x4 acc[2][2] = {};
    for (int kt = 0; kt < EMB / 32; ++kt) {
        uint4 av = *(const uint4*)(Aptr + kt * 32);
        uint4 bv = *(const uint4*)(Bptr + kt * 32);
        *(uint4*)&As[lr][lc] = av;
        *(uint4*)&Bs[lr][lc] = bv;
        __syncthreads();
        bf16x8 a0 = *(const bf16x8*)&As[wm + col][quad * 8];
        bf16x8 a1 = *(const bf16x8*)&As[wm + 16 + col][quad * 8];
        bf16x8 b0 = *(const bf16x8*)&Bs[wn + col][quad * 8];
        bf16x8 b1 = *(const bf16x8*)&Bs[wn + 16 + col][quad * 8];
        acc[0][0] = __builtin_amdgcn_mfma_f32_16x16x32_bf16(a0, b0, acc[0][0], 0, 0, 0);
        acc[0][1] = __builtin_amdgcn_mfma_f32_16x16x32_bf16(a0, b1, acc[0][1], 0, 0, 0);
        acc[1][0] = __builtin_amdgcn_mfma_f32_16x16x32_bf16(a1, b0, acc[1][0], 0, 0, 0);
        acc[1][1] = __builtin_amdgcn_mfma_f32_16x16x32_bf16(a1, b1, acc[1][1], 0, 0, 0);
        __syncthreads();
    }

    for (int i = 0; i < 2; ++i)
        for (int j = 0; j < 2; ++j)
            for (int r = 0; r < 4; ++r) {
                int m = m0 + wm + i * 16 + quad * 4 + r;
                int n = n0 + wn + j * 16 + col;
                out[(size_t)m * EMB + n] = acc[i][j][r] + bias[n];
            }
}

extern "C" void kernel_launch(void* const* d_in, const int* in_sizes, int n_in,
                              void* d_out, int out_size, void* d_ws, size_t ws_size,
                              hipStream_t stream) {
    const float* x      = (const float*)d_in[0];  // [4,2048,1024]
    const float* W_qkv  = (const float*)d_in[1];  // [3072,1024]
    const float* b_qkv  = (const float*)d_in[2];  // [3072]
    const float* W_proj = (const float*)d_in[3];  // [1024,1024]
    const float* b_proj = (const float*)d_in[4];  // [1024]
    float* out = (float*)d_out;

    ushort* ws     = (ushort*)d_ws;
    ushort* Xb     = ws;                 // 8388608  (reused as Yb after qkv gemm)
    ushort* Yb     = ws;
    ushort* Wqkvb  = ws + 8388608;       // 3145728
    ushort* Wprojb = ws + 11534336;      // 1048576
    ushort* Qb     = ws + 12582912;      // 8388608
    ushort* Kb     = ws + 20971520;      // 8388608
    ushort* Vt     = ws + 29360128;      // 8388608
    // total: 37748736 ushorts = 72 MB

    cvt_f32_bf16<<<8192, 256, 0, stream>>>((const float4*)x,      Xb,     2097152);
    cvt_f32_bf16<<<3072, 256, 0, stream>>>((const float4*)W_qkv,  Wqkvb,  786432);
    cvt_f32_bf16<<<1024, 256, 0, stream>>>((const float4*)W_proj, Wprojb, 262144);

    gemm_qkv<<<dim3(128, 48), 256, 0, stream>>>(Xb, Wqkvb, b_qkv, Qb, Kb, Vt);
    attn<<<dim3(64, 32), 256, 0, stream>>>(Qb, Kb, Vt, Yb);
    gemm_proj<<<dim3(128, 16), 256, 0, stream>>>(Yb, Wprojb, b_proj, out);
}

// Round 2
// 439.689 us; speedup vs baseline: 1.1882x; 1.1882x over previous
//
#include <hip/hip_runtime.h>
#include <hip/hip_bf16.h>

typedef __attribute__((ext_vector_type(4))) float f32x4;
typedef __attribute__((ext_vector_type(8))) __bf16 bf16x8;

#define EMB 1024
#define NHEAD 16
#define HDIM 64
#define SEQ 2048
#define BATCH 4

__device__ __forceinline__ unsigned short f2bf(float f) {
    unsigned int u = __builtin_bit_cast(unsigned int, f);
    u = (u + 0x7fffu + ((u >> 16) & 1u)) >> 16;
    return (unsigned short)u;
}

__device__ __forceinline__ void async_copy16(const ushort* g, ushort* l) {
    __builtin_amdgcn_global_load_lds(
        (const __attribute__((address_space(1))) void*)g,
        (__attribute__((address_space(3))) void*)l,
        16, 0, 0);
}

// ---------------- fp32 -> bf16 convert ----------------
__global__ void cvt_f32_bf16(const float4* __restrict__ in, ushort* __restrict__ out, int n4) {
    int i = blockIdx.x * 256 + threadIdx.x;
    if (i < n4) {
        float4 v = in[i];
        ushort4 o;
        o.x = f2bf(v.x); o.y = f2bf(v.y); o.z = f2bf(v.z); o.w = f2bf(v.w);
        ((ushort4*)out)[i] = o;
    }
}

// ================= 128x128-tile GEMM core (m97 structure) =================
// A [M,1024] bf16, W [N,1024] bf16 (row-major, i.e. B^T input).
// 256 threads = 4 waves; wave computes 64x64 via 4x4 of 16x16x32 MFMA.
// LDS: unpadded [128][32] bf16; XOR swizzle on global source address so
// fragment ds_read_b128 lands 2-way (free) instead of 8-way.

#define GEMM_STAGE(Asrc, Bsrc, m0, n0, kt)                                        \
    {                                                                             \
        _Pragma("unroll")                                                         \
        for (int j = 0; j < 2; ++j) {                                             \
            int row = wave * 32 + j * 16 + (lane >> 2);                           \
            int kc  = (lane & 3) ^ ((row >> 1) & 3);                              \
            async_copy16(Asrc + (size_t)(m0 + row) * EMB + kt + kc * 8,           \
                         As + (wave * 32 + j * 16) * 32);                         \
            async_copy16(Bsrc + (size_t)(n0 + row) * EMB + kt + kc * 8,           \
                         Bs + (wave * 32 + j * 16) * 32);                         \
        }                                                                         \
    }

#define GEMM_BODY(Asrc, Bsrc, m0, n0)                                             \
    f32x4 acc[4][4] = {};                                                         \
    for (int kt = 0; kt < EMB; kt += 32) {                                        \
        GEMM_STAGE(Asrc, Bsrc, m0, n0, kt)                                        \
        __syncthreads();                                                          \
        bf16x8 a[4], b[4];                                                        \
        _Pragma("unroll")                                                         \
        for (int i = 0; i < 4; ++i) {                                             \
            int r = wm + i * 16 + col;                                            \
            a[i] = *(const bf16x8*)&As[r * 32 + (quad ^ ((r >> 1) & 3)) * 8];     \
            int c = wn + i * 16 + col;                                            \
            b[i] = *(const bf16x8*)&Bs[c * 32 + (quad ^ ((c >> 1) & 3)) * 8];     \
        }                                                                         \
        _Pragma("unroll")                                                         \
        for (int i = 0; i < 4; ++i)                                               \
            _Pragma("unroll")                                                     \
            for (int j = 0; j < 4; ++j)                                           \
                acc[i][j] = __builtin_amdgcn_mfma_f32_16x16x32_bf16(              \
                    a[i], b[j], acc[i][j], 0, 0, 0);                              \
        __syncthreads();                                                          \
    }

// ---------------- QKV GEMM + bias + scatter to Q/K/Vt ----------------
__global__ __launch_bounds__(256) void gemm_qkv(
    const ushort* __restrict__ A,     // [8192,1024]
    const ushort* __restrict__ W,     // [3072,1024]
    const float*  __restrict__ bias,  // [3072]
    ushort* __restrict__ Qb, ushort* __restrict__ Kb, ushort* __restrict__ Vt)
{
    __shared__ ushort As[128 * 32];
    __shared__ ushort Bs[128 * 32];
    const int tid  = threadIdx.x;
    const int lane = tid & 63;
    const int wave = tid >> 6;
    const int col  = lane & 15;
    const int quad = lane >> 4;
    const int m0 = blockIdx.x * 128;
    const int n0 = blockIdx.y * 128;
    const int wm = (wave >> 1) * 64;
    const int wn = (wave & 1) * 64;

    GEMM_BODY(A, W, m0, n0)

    #pragma unroll
    for (int i = 0; i < 4; ++i)
        #pragma unroll
        for (int j = 0; j < 4; ++j)
            #pragma unroll
            for (int r = 0; r < 4; ++r) {
                int m = m0 + wm + i * 16 + quad * 4 + r;   // b*2048+s
                int n = n0 + wn + j * 16 + col;            // 0..3071
                float v = acc[i][j][r] + bias[n];
                unsigned short bv = f2bf(v);
                int which = n >> 10;
                int e = n & 1023;
                int h = e >> 6, d = e & 63;
                int b = m >> 11, s = m & 2047;
                size_t bh = (size_t)(b * NHEAD + h);
                if (which == 0)      Qb[(bh * SEQ + s) * HDIM + d] = bv;
                else if (which == 1) Kb[(bh * SEQ + s) * HDIM + d] = bv;
                else                 Vt[(bh * HDIM + d) * SEQ + s] = bv;
            }
}

// ---------------- Output proj + bias -> fp32 out ----------------
__global__ __launch_bounds__(256) void gemm_proj(
    const ushort* __restrict__ A,     // [8192,1024]
    const ushort* __restrict__ W,     // [1024,1024]
    const float*  __restrict__ bias,  // [1024]
    float* __restrict__ out)          // [8192,1024]
{
    __shared__ ushort As[128 * 32];
    __shared__ ushort Bs[128 * 32];
    const int tid  = threadIdx.x;
    const int lane = tid & 63;
    const int wave = tid >> 6;
    const int col  = lane & 15;
    const int quad = lane >> 4;
    const int m0 = blockIdx.x * 128;
    const int n0 = blockIdx.y * 128;
    const int wm = (wave >> 1) * 64;
    const int wn = (wave & 1) * 64;

    GEMM_BODY(A, W, m0, n0)

    #pragma unroll
    for (int i = 0; i < 4; ++i)
        #pragma unroll
        for (int j = 0; j < 4; ++j)
            #pragma unroll
            for (int r = 0; r < 4; ++r) {
                int m = m0 + wm + i * 16 + quad * 4 + r;
                int n = n0 + wn + j * 16 + col;
                out[(size_t)m * EMB + n] = acc[i][j][r] + bias[n];
            }
}

// ---------------- Flash attention (causal), 64-key tile, no barriers ----------------
// grid: 2048 blocks, longest-first: qb = 31 - (blockIdx.x>>6), bh = blockIdx.x&63.
// block 256 = 4 waves x 16 q-rows. P transpose stays wave-local (no __syncthreads).
__global__ __launch_bounds__(256) void attn(
    const ushort* __restrict__ Qb, const ushort* __restrict__ Kb,
    const ushort* __restrict__ Vt, ushort* __restrict__ Yb)
{
    __shared__ ushort P[4][16][72];   // per-wave 16x64, stride 72 (144B = 9x16B)
    const int lane = threadIdx.x & 63;
    const int wave = threadIdx.x >> 6;
    const int col  = lane & 15;
    const int quad = lane >> 4;
    const int bh   = blockIdx.x & 63;        // b*16+h
    const int qb   = 31 - (blockIdx.x >> 6); // longest blocks dispatch first
    const int q0   = qb * 64 + wave * 16;

    const ushort* Qh = Qb + (size_t)bh * SEQ * HDIM;
    const ushort* Kh = Kb + (size_t)bh * SEQ * HDIM;
    const ushort* Vh = Vt + (size_t)bh * HDIM * SEQ;

    bf16x8 qf0 = *(const bf16x8*)(Qh + (q0 + col) * HDIM + quad * 8);
    bf16x8 qf1 = *(const bf16x8*)(Qh + (q0 + col) * HDIM + 32 + quad * 8);

    f32x4 o[4] = {};
    float mrun[4], lrun[4];
    #pragma unroll
    for (int r = 0; r < 4; ++r) { mrun[r] = -INFINITY; lrun[r] = 0.f; }

    for (int kt = 0; kt <= qb; ++kt) {
        const int k0 = kt * 64;
        // ---- scores: Q @ K^T for 64 key columns ----
        f32x4 s[4];
        #pragma unroll
        for (int j = 0; j < 4; ++j) {
            const ushort* kb = Kh + (size_t)(k0 + j * 16 + col) * HDIM + quad * 8;
            bf16x8 kf0 = *(const bf16x8*)(kb);
            bf16x8 kf1 = *(const bf16x8*)(kb + 32);
            f32x4 z = {0.f, 0.f, 0.f, 0.f};
            s[j] = __builtin_amdgcn_mfma_f32_16x16x32_bf16(qf0, kf0, z, 0, 0, 0);
            s[j] = __builtin_amdgcn_mfma_f32_16x16x32_bf16(qf1, kf1, s[j], 0, 0, 0);
        }

        // ---- online softmax over 64 columns ----
        float alpha[4], p[4][4];
        #pragma unroll
        for (int r = 0; r < 4; ++r) {
            int row = q0 + quad * 4 + r;
            float v[4];
            float mx = -INFINITY;
            #pragma unroll
            for (int j = 0; j < 4; ++j) {
                int c = k0 + j * 16 + col;
                v[j] = (c <= row) ? s[j][r] * 0.125f : -INFINITY;
                mx = fmaxf(mx, v[j]);
            }
            #pragma unroll
            for (int off = 1; off < 16; off <<= 1)
                mx = fmaxf(mx, __shfl_xor(mx, off, 64));
            float mnew = fmaxf(mrun[r], mx);
            alpha[r] = __expf(mrun[r] - mnew);
            float rs = 0.f;
            #pragma unroll
            for (int j = 0; j < 4; ++j) {
                p[j][r] = __expf(v[j] - mnew);
                rs += p[j][r];
            }
            #pragma unroll
            for (int off = 1; off < 16; off <<= 1)
                rs += __shfl_xor(rs, off, 64);
            lrun[r] = lrun[r] * alpha[r] + rs;
            mrun[r] = mnew;
        }
        #pragma unroll
        for (int dt = 0; dt < 4; ++dt)
            #pragma unroll
            for (int r = 0; r < 4; ++r)
                o[dt][r] *= alpha[r];

        // ---- P: C-layout -> LDS -> A-operand layout (wave-local, no barrier) ----
        #pragma unroll
        for (int j = 0; j < 4; ++j)
            #pragma unroll
            for (int r = 0; r < 4; ++r)
                P[wave][quad * 4 + r][j * 16 + col] = f2bf(p[j][r]);
        __threadfence_block();   // LDS fence within the wave (lgkmcnt drain)
        bf16x8 pf0 = *(const bf16x8*)&P[wave][col][quad * 8];
        bf16x8 pf1 = *(const bf16x8*)&P[wave][col][32 + quad * 8];

        // ---- O += P @ V ----
        #pragma unroll
        for (int dt = 0; dt < 4; ++dt) {
            const ushort* vb = Vh + (size_t)(dt * 16 + col) * SEQ + k0;
            bf16x8 vf0 = *(const bf16x8*)(vb + quad * 8);
            bf16x8 vf1 = *(const bf16x8*)(vb + 32 + quad * 8);
            o[dt] = __builtin_amdgcn_mfma_f32_16x16x32_bf16(pf0, vf0, o[dt], 0, 0, 0);
            o[dt] = __builtin_amdgcn_mfma_f32_16x16x32_bf16(pf1, vf1, o[dt], 0, 0, 0);
        }
    }

    // ---- epilogue: O/l -> Y[b, s, h*64+d] bf16 ----
    const int b = bh >> 4, h = bh & 15;
    #pragma unroll
    for (int r = 0; r < 4; ++r) {
        float inv = 1.f / lrun[r];
        int srow = q0 + quad * 4 + r;
        size_t base = ((size_t)(b * SEQ + srow)) * EMB + h * HDIM;
        #pragma unroll
        for (int dt = 0; dt < 4; ++dt)
            Yb[base + dt * 16 + col] = f2bf(o[dt][r] * inv);
    }
}

extern "C" void kernel_launch(void* const* d_in, const int* in_sizes, int n_in,
                              void* d_out, int out_size, void* d_ws, size_t ws_size,
                              hipStream_t stream) {
    const float* x      = (const float*)d_in[0];  // [4,2048,1024]
    const float* W_qkv  = (const float*)d_in[1];  // [3072,1024]
    const float* b_qkv  = (const float*)d_in[2];  // [3072]
    const float* W_proj = (const float*)d_in[3];  // [1024,1024]
    const float* b_proj = (const float*)d_in[4];  // [1024]
    float* out = (float*)d_out;

    ushort* ws     = (ushort*)d_ws;
    ushort* Xb     = ws;                 // 8388608  (reused as Yb after qkv gemm)
    ushort* Yb     = ws;
    ushort* Wqkvb  = ws + 8388608;       // 3145728
    ushort* Wprojb = ws + 11534336;      // 1048576
    ushort* Qb     = ws + 12582912;      // 8388608
    ushort* Kb     = ws + 20971520;      // 8388608
    ushort* Vt     = ws + 29360128;      // 8388608
    // total: 37748736 ushorts = 72 MB

    cvt_f32_bf16<<<8192, 256, 0, stream>>>((const float4*)x,      Xb,     2097152);
    cvt_f32_bf16<<<3072, 256, 0, stream>>>((const float4*)W_qkv,  Wqkvb,  786432);
    cvt_f32_bf16<<<1024, 256, 0, stream>>>((const float4*)W_proj, Wprojb, 262144);

    gemm_qkv<<<dim3(64, 24), 256, 0, stream>>>(Xb, Wqkvb, b_qkv, Qb, Kb, Vt);
    attn<<<2048, 256, 0, stream>>>(Qb, Kb, Vt, Yb);
    gemm_proj<<<dim3(64, 8), 256, 0, stream>>>(Yb, Wprojb, b_proj, out);
}